// Round 1
// baseline (1004.200 us; speedup 1.0000x reference)
//
#include <hip/hip_runtime.h>
#include <math.h>

// Problem constants (B=2, H=W=48, C=E=256, NH=8, GH=1)
#define NTOK 2304              // H*W
#define NS   4608              // B*NTOK
#define CH   256               // C == E == E*GH
#define NHEAD 8
#define DH   32

// ---------------- LayerNorm kernels ----------------

// LN over channel dim while transposing [B,C,N] -> [Ns, C]
__global__ __launch_bounds__(256) void k_ln_tok(const float* __restrict__ x,
    const float* __restrict__ g, const float* __restrict__ be, float* __restrict__ out)
{
    int row = blockIdx.x;              // b*NTOK + n
    int b = row / NTOK, n = row - b * NTOK;
    int c = threadIdx.x;
    float v = x[((size_t)b * CH + c) * NTOK + n];
    __shared__ float s1[256], s2[256];
    s1[c] = v; s2[c] = v * v;
    __syncthreads();
    #pragma unroll
    for (int st = 128; st > 0; st >>= 1) {
        if (c < st) { s1[c] += s1[c + st]; s2[c] += s2[c + st]; }
        __syncthreads();
    }
    float mu = s1[0] * (1.f / CH);
    float var = s2[0] * (1.f / CH) - mu * mu;
    float r = rsqrtf(var + 1e-5f);
    out[(size_t)row * CH + c] = (v - mu) * r * g[c] + be[c];
}

// plain LN: fp32 [NS,256] -> fp32 [NS,256]
__global__ __launch_bounds__(256) void k_ln(const float* __restrict__ in,
    const float* __restrict__ g, const float* __restrict__ be, float* __restrict__ out)
{
    int row = blockIdx.x;
    int c = threadIdx.x;
    float v = in[(size_t)row * CH + c];
    __shared__ float s1[256], s2[256];
    s1[c] = v; s2[c] = v * v;
    __syncthreads();
    #pragma unroll
    for (int st = 128; st > 0; st >>= 1) {
        if (c < st) { s1[c] += s1[c + st]; s2[c] += s2[c + st]; }
        __syncthreads();
    }
    float mu = s1[0] * (1.f / CH);
    float var = s2[0] * (1.f / CH) - mu * mu;
    float r = rsqrtf(var + 1e-5f);
    out[(size_t)row * CH + c] = (v - mu) * r * g[c] + be[c];
}

// final LN + transpose to [B, E, H*W]
__global__ __launch_bounds__(256) void k_ln_out(const float* __restrict__ in,
    const float* __restrict__ g, const float* __restrict__ be, float* __restrict__ out)
{
    int row = blockIdx.x;
    int b = row / NTOK, n = row - b * NTOK;
    int c = threadIdx.x;
    float v = in[(size_t)row * CH + c];
    __shared__ float s1[256], s2[256];
    s1[c] = v; s2[c] = v * v;
    __syncthreads();
    #pragma unroll
    for (int st = 128; st > 0; st >>= 1) {
        if (c < st) { s1[c] += s1[c + st]; s2[c] += s2[c + st]; }
        __syncthreads();
    }
    float mu = s1[0] * (1.f / CH);
    float var = s2[0] * (1.f / CH) - mu * mu;
    float r = rsqrtf(var + 1e-5f);
    float val = (v - mu) * r * g[c] + be[c];
    out[((size_t)b * CH + c) * NTOK + n] = val;
}

// ---------------- GEMM: out = act(A[M,256] @ W[256,256] + bias (+resid)) ----------------
// ACT: 0 = none, 1 = exact gelu
template<int ACT>
__global__ __launch_bounds__(256) void k_gemm(const float* __restrict__ A,
    const float* __restrict__ W, const float* __restrict__ bias,
    const float* __restrict__ resid, float* __restrict__ out)
{
    __shared__ float As[16][68];   // [k][m], padded
    __shared__ float Bs[16][64];   // [k][n]
    int t = threadIdx.x;
    int bm = blockIdx.x * 64;
    int bn = blockIdx.y * 64;
    int tm = (t >> 4) * 4;
    int tc = (t & 15) * 4;
    int ar = t >> 2, ac4 = (t & 3) * 4;
    int br = t >> 4, bc4 = (t & 15) * 4;
    float acc[4][4];
    #pragma unroll
    for (int i = 0; i < 4; i++)
        #pragma unroll
        for (int j = 0; j < 4; j++) acc[i][j] = 0.f;

    for (int kk = 0; kk < 256; kk += 16) {
        float4 av = *(const float4*)&A[(size_t)(bm + ar) * 256 + kk + ac4];
        As[ac4 + 0][ar] = av.x; As[ac4 + 1][ar] = av.y;
        As[ac4 + 2][ar] = av.z; As[ac4 + 3][ar] = av.w;
        float4 bv = *(const float4*)&W[(size_t)(kk + br) * 256 + bn + bc4];
        *(float4*)&Bs[br][bc4] = bv;
        __syncthreads();
        #pragma unroll
        for (int k = 0; k < 16; k++) {
            float4 a4 = *(const float4*)&As[k][tm];
            float4 b4 = *(const float4*)&Bs[k][tc];
            acc[0][0] += a4.x * b4.x; acc[0][1] += a4.x * b4.y; acc[0][2] += a4.x * b4.z; acc[0][3] += a4.x * b4.w;
            acc[1][0] += a4.y * b4.x; acc[1][1] += a4.y * b4.y; acc[1][2] += a4.y * b4.z; acc[1][3] += a4.y * b4.w;
            acc[2][0] += a4.z * b4.x; acc[2][1] += a4.z * b4.y; acc[2][2] += a4.z * b4.z; acc[2][3] += a4.z * b4.w;
            acc[3][0] += a4.w * b4.x; acc[3][1] += a4.w * b4.y; acc[3][2] += a4.w * b4.z; acc[3][3] += a4.w * b4.w;
        }
        __syncthreads();
    }
    #pragma unroll
    for (int i = 0; i < 4; i++) {
        int row = bm + tm + i;
        float4 o4;
        float* pv = (float*)&o4;
        #pragma unroll
        for (int j = 0; j < 4; j++) {
            int col = bn + tc + j;
            float vv = acc[i][j];
            if (bias)  vv += bias[col];
            if (resid) vv += resid[(size_t)row * 256 + col];
            if (ACT == 1) vv = 0.5f * vv * (1.f + erff(vv * 0.70710678118654752f));
            pv[j] = vv;
        }
        *(float4*)&out[(size_t)row * 256 + bn + tc] = o4;
    }
}

// ---------------- Attention: flash, one query per lane, split-K across 4 waves ----------------
__global__ __launch_bounds__(256) void k_attn(const float* __restrict__ Q,
    const float* __restrict__ K, const float* __restrict__ V, float* __restrict__ O)
{
    int bh = blockIdx.y;
    int b = bh >> 3, h = bh & 7;
    int lane = threadIdx.x & 63;
    int w = threadIdx.x >> 6;
    int qi = blockIdx.x * 64 + lane;   // 36*64 = 2304, always in range
    size_t headoff = (size_t)b * NTOK * 256 + h * 32;

    float qr[32];
    const float* qp = Q + headoff + (size_t)qi * 256;
    #pragma unroll
    for (int d0 = 0; d0 < 32; d0 += 4) {
        float4 t4 = *(const float4*)(qp + d0);
        qr[d0] = t4.x; qr[d0 + 1] = t4.y; qr[d0 + 2] = t4.z; qr[d0 + 3] = t4.w;
    }
    float m = -1e30f, l = 0.f;
    float acc[32];
    #pragma unroll
    for (int d = 0; d < 32; d++) acc[d] = 0.f;
    const float scale = 0.17677669529663687f;   // 1/sqrt(32)

    int k0 = w * (NTOK / 4), k1 = k0 + (NTOK / 4);
    for (int kk = k0; kk < k1; ++kk) {
        const float* kp = K + headoff + (size_t)kk * 256;
        float s = 0.f;
        #pragma unroll
        for (int d0 = 0; d0 < 32; d0 += 4) {
            float4 kv = *(const float4*)(kp + d0);
            s += qr[d0] * kv.x + qr[d0 + 1] * kv.y + qr[d0 + 2] * kv.z + qr[d0 + 3] * kv.w;
        }
        s *= scale;
        float mn = fmaxf(m, s);
        float corr = __expf(m - mn);
        float p = __expf(s - mn);
        l = l * corr + p;
        const float* vp = V + headoff + (size_t)kk * 256;
        #pragma unroll
        for (int d0 = 0; d0 < 32; d0 += 4) {
            float4 vv = *(const float4*)(vp + d0);
            acc[d0]     = acc[d0]     * corr + p * vv.x;
            acc[d0 + 1] = acc[d0 + 1] * corr + p * vv.y;
            acc[d0 + 2] = acc[d0 + 2] * corr + p * vv.z;
            acc[d0 + 3] = acc[d0 + 3] * corr + p * vv.w;
        }
        m = mn;
    }

    __shared__ float sm[4][64], sl[4][64];
    __shared__ float sacc[4][64][33];
    sm[w][lane] = m; sl[w][lane] = l;
    #pragma unroll
    for (int d = 0; d < 32; d++) sacc[w][lane][d] = acc[d];
    __syncthreads();

    if (threadIdx.x < 64) {
        int tq = threadIdx.x;
        int q2 = blockIdx.x * 64 + tq;
        float M = fmaxf(fmaxf(sm[0][tq], sm[1][tq]), fmaxf(sm[2][tq], sm[3][tq]));
        float wgt[4]; float L = 0.f;
        #pragma unroll
        for (int s = 0; s < 4; s++) { wgt[s] = __expf(sm[s][tq] - M); L += sl[s][tq] * wgt[s]; }
        float invL = 1.f / L;
        float* op = O + headoff + (size_t)q2 * 256;
        #pragma unroll
        for (int d = 0; d < 32; d++) {
            float od = sacc[0][tq][d] * wgt[0] + sacc[1][tq][d] * wgt[1]
                     + sacc[2][tq][d] * wgt[2] + sacc[3][tq][d] * wgt[3];
            op[d] = od * invL;
        }
    }
}

// ---------------- GAT pieces ----------------

// a_src[i] = sum_d h[i,d]*att_src[d]; a_dst likewise
__global__ __launch_bounds__(256) void k_attvec(const float* __restrict__ h,
    const float* __restrict__ wsrc, const float* __restrict__ wdst,
    float* __restrict__ a_src, float* __restrict__ a_dst)
{
    int node = blockIdx.x;
    int c = threadIdx.x;
    float hv = h[(size_t)node * CH + c];
    __shared__ float s1[256], s2[256];
    s1[c] = hv * wsrc[c]; s2[c] = hv * wdst[c];
    __syncthreads();
    #pragma unroll
    for (int st = 128; st > 0; st >>= 1) {
        if (c < st) { s1[c] += s1[c + st]; s2[c] += s2[c + st]; }
        __syncthreads();
    }
    if (c == 0) { a_src[node] = s1[0]; a_dst[node] = s2[0]; }
}

// build fixed-stride CSR (max degree on this grid graph is 9, slot=16)
__global__ void k_fill_edges(const int* __restrict__ ei, int Eed,
    int* __restrict__ deg, int* __restrict__ csr)
{
    int e = blockIdx.x * 256 + threadIdx.x;
    if (e >= Eed) return;
    int src = ei[e];
    int dst = ei[Eed + e];
    int pos = atomicAdd(&deg[dst], 1);
    if (pos < 16) csr[dst * 16 + pos] = src;
}

// per-dst edge softmax + aggregation + elu + residual (writes nf in place)
__global__ __launch_bounds__(256) void k_gat_agg(const int* __restrict__ deg,
    const int* __restrict__ csr, const float* __restrict__ a_src,
    const float* __restrict__ a_dst, const float* __restrict__ h,
    const float* __restrict__ gbias, float* __restrict__ nf)
{
    int dst = blockIdx.x;
    int t = threadIdx.x;
    __shared__ float logit[16];
    __shared__ float alpha[16];
    __shared__ int srcs[16];
    int cnt = deg[dst]; if (cnt > 16) cnt = 16;
    if (t < cnt) {
        int s = csr[dst * 16 + t];
        srcs[t] = s;
        float lg = a_src[s] + a_dst[dst];
        logit[t] = lg > 0.f ? lg : 0.2f * lg;
    }
    __syncthreads();
    if (t == 0) {
        float mx = -1e30f;
        for (int i = 0; i < cnt; i++) mx = fmaxf(mx, logit[i]);
        float dn = 0.f;
        for (int i = 0; i < cnt; i++) { float ex = __expf(logit[i] - mx); alpha[i] = ex; dn += ex; }
        float inv = 1.f / (dn + 1e-16f);
        for (int i = 0; i < cnt; i++) alpha[i] *= inv;
    }
    __syncthreads();
    float accv = 0.f;
    for (int i = 0; i < cnt; i++) accv += alpha[i] * h[(size_t)srcs[i] * CH + t];
    float val = accv + gbias[t];
    val = val > 0.f ? val : expm1f(val);
    nf[(size_t)dst * CH + t] += val;
}

// ---------------- orchestration ----------------
extern "C" void kernel_launch(void* const* d_in, const int* in_sizes, int n_in,
                              void* d_out, int out_size, void* d_ws, size_t ws_size,
                              hipStream_t stream)
{
    const float* x_cnn   = (const float*)d_in[0];
    const int*   edge    = (const int*)d_in[1];
    const float* norm1_g = (const float*)d_in[2];
    const float* norm1_b = (const float*)d_in[3];
    const float* proj_w  = (const float*)d_in[4];
    const float* proj_b  = (const float*)d_in[5];
    const float* wq      = (const float*)d_in[6];
    const float* bq      = (const float*)d_in[7];
    const float* wk      = (const float*)d_in[8];
    const float* bk      = (const float*)d_in[9];
    const float* wv      = (const float*)d_in[10];
    const float* bv      = (const float*)d_in[11];
    const float* wo      = (const float*)d_in[12];
    const float* bo      = (const float*)d_in[13];
    const float* norm2_g = (const float*)d_in[14];
    const float* norm2_b = (const float*)d_in[15];
    const float* gpl_w   = (const float*)d_in[16];
    const float* gpl_b   = (const float*)d_in[17];
    const float* gat_w   = (const float*)d_in[18];
    const float* att_src = (const float*)d_in[19];
    const float* att_dst = (const float*)d_in[20];
    const float* gat_bias= (const float*)d_in[21];
    const float* norm3_g = (const float*)d_in[22];
    const float* norm3_b = (const float*)d_in[23];
    const float* mlp_w1  = (const float*)d_in[24];
    const float* mlp_b1  = (const float*)d_in[25];
    const float* mlp_w2  = (const float*)d_in[26];
    const float* mlp_b2  = (const float*)d_in[27];
    const float* fn_g    = (const float*)d_in[28];
    const float* fn_b    = (const float*)d_in[29];

    int Eed = in_sizes[1] / 2;
    float* out = (float*)d_out;

    const size_t NB = (size_t)NS * CH;   // 1,179,648 floats per buffer
    float* ws   = (float*)d_ws;
    float* bufA = ws + 0 * NB;
    float* bufB = ws + 1 * NB;
    float* bufC = ws + 2 * NB;
    float* bufD = ws + 3 * NB;
    float* bufE = ws + 4 * NB;
    float* a_src = ws + 5 * NB;
    float* a_dst = a_src + NS;
    int*   deg   = (int*)(a_dst + NS);
    int*   csr   = deg + NS;             // NS*16 ints
    // total ws use: 5*4.72MB + ~0.35MB ≈ 24 MB

    dim3 g72(72, 4);

    // 1. tokenize + LN1 -> bufA
    k_ln_tok<<<NS, 256, 0, stream>>>(x_cnn, norm1_g, norm1_b, bufA);
    // 2. xv = bufA @ proj + proj_b -> bufB
    k_gemm<0><<<g72, 256, 0, stream>>>(bufA, proj_w, proj_b, nullptr, bufB);
    // 3. q,k,v
    k_gemm<0><<<g72, 256, 0, stream>>>(bufB, wq, bq, nullptr, bufC);
    k_gemm<0><<<g72, 256, 0, stream>>>(bufB, wk, bk, nullptr, bufD);
    k_gemm<0><<<g72, 256, 0, stream>>>(bufB, wv, bv, nullptr, bufE);
    // 4. attention -> bufA
    k_attn<<<dim3(36, 16), 256, 0, stream>>>(bufC, bufD, bufE, bufA);
    // 5. nf = bufB + bufA @ wo + bo  (in-place into bufB)
    k_gemm<0><<<g72, 256, 0, stream>>>(bufA, wo, bo, bufB, bufB);
    // 6. ln2 -> bufC
    k_ln<<<NS, 256, 0, stream>>>(bufB, norm2_g, norm2_b, bufC);
    // 7. xg = bufC @ gpl_w + gpl_b -> bufD
    k_gemm<0><<<g72, 256, 0, stream>>>(bufC, gpl_w, gpl_b, nullptr, bufD);
    // 8. h = bufD @ gat_w -> bufE
    k_gemm<0><<<g72, 256, 0, stream>>>(bufD, gat_w, nullptr, nullptr, bufE);
    // 9. a_src/a_dst
    k_attvec<<<NS, 256, 0, stream>>>(bufE, att_src, att_dst, a_src, a_dst);
    // 10. CSR build
    hipMemsetAsync(deg, 0, NS * sizeof(int), stream);
    k_fill_edges<<<(Eed + 255) / 256, 256, 0, stream>>>(edge, Eed, deg, csr);
    // 11. GAT aggregate + elu + residual (bufB updated in place)
    k_gat_agg<<<NS, 256, 0, stream>>>(deg, csr, a_src, a_dst, bufE, gat_bias, bufB);
    // 12. ln3 -> bufC
    k_ln<<<NS, 256, 0, stream>>>(bufB, norm3_g, norm3_b, bufC);
    // 13. mlp1 = gelu(bufC @ mlp_w1 + b1) -> bufD
    k_gemm<1><<<g72, 256, 0, stream>>>(bufC, mlp_w1, mlp_b1, nullptr, bufD);
    // 14. y_pre = bufC + bufD @ mlp_w2 + b2 -> bufA
    k_gemm<0><<<g72, 256, 0, stream>>>(bufD, mlp_w2, mlp_b2, bufC, bufA);
    // 15. final LN + transpose -> out
    k_ln_out<<<NS, 256, 0, stream>>>(bufA, fn_g, fn_b, out);
}